// Round 7
// baseline (685.024 us; speedup 1.0000x reference)
//
#include <hip/hip_runtime.h>
#include <hip/hip_bf16.h>

// MSAAttentionBlock round 8: round-5 base (471 µs, VGPR 56, zero scratch) +
// software pipelining expressed ONLY with named scalar registers.
// Round-6's template/array pipeline hit the 64-VGPR cap and re-spilled
// (WRITE_SIZE +128 MB); this version budgets live regs per phase:
//   stage 1: GN=2/2/1 passes, depth-2 named prefetch (live ~50)
//   stage 3: GN=2 x2 passes,  depth-2 named prefetch (live ~50)
//   stage 4: GN=1 loops,      depth-3 named rotation (live ~30)
// Stage 0/2, layouts, barriers identical to round 5.
// Scratch tripwire: WRITE_SIZE must stay exactly 131072 KB.

typedef __bf16 bf16;
typedef __bf16 bf16x8 __attribute__((ext_vector_type(8)));
typedef float f32x4 __attribute__((ext_vector_type(4)));

#define MFMA(a, b, c) __builtin_amdgcn_mfma_f32_16x16x32_bf16((a), (b), (c), 0, 0, 0)

#define THREADS 1024
#define TILE 32

constexpr int CIN = 256;

// packed-weight regions, in 8-element chunks (chunk = 16 B)
// layout per matrix: chunk lc = (nt*KT + kt)*64 + lane ; elems at lc*8
//   element j of chunk: B[k = kt*32 + (lane>>4)*8 + j][n = nt*16 + (lane&15)]
constexpr int CH_WQ = 0;                // 256x512  -> 16384 chunks, KT=8
constexpr int CH_WK = 16384;            // 256x512
constexpr int CH_WV = 32768;            // 256x256  -> 8192
constexpr int CH_W1 = 40960;            // 256x1024 -> 32768
constexpr int CH_WO = 73728;            // 1024x256 -> 32768, KT=32
constexpr int CH_WC = 106496;           // 256x256  -> 8192
constexpr int CH_TOT = 114688;          // * 16 B = 1.75 MB

// LDS layout (bf16 element offsets)
constexpr int L_XF  = 0;                // x A-frags:  2*8*64*8 = 8192
constexpr int L_AOF = 8192;             // ao A-frags: 8192
constexpr int L_C   = 16384;            // overlay region
constexpr int L_QS  = L_C;              // q plain [32][528]
constexpr int L_KS  = L_C + 16896;      // k plain [32][528]
constexpr int L_VS  = L_C + 33792;      // v plain [32][272]
constexpr int L_INTF = L_C;             // inter A-frags 2*32*64*8 = 32768 (aliases q/k/v)
constexpr int LDS_ELEMS = 16384 + 42496;   // 58880 bf16 = 117760 B -> 1 block/CU, 16 waves

__global__ void pack_w(const float* __restrict__ Wq, const float* __restrict__ Wk,
                       const float* __restrict__ Wv, const float* __restrict__ W1,
                       const float* __restrict__ Wo, const float* __restrict__ Wc,
                       bf16* __restrict__ ws) {
    int c = blockIdx.x * 256 + threadIdx.x;
    if (c >= CH_TOT) return;
    const float* W; int N, KT, lc;
    if (c < CH_WK)      { W = Wq; N = 512;  KT = 8;  lc = c - CH_WQ; }
    else if (c < CH_WV) { W = Wk; N = 512;  KT = 8;  lc = c - CH_WK; }
    else if (c < CH_W1) { W = Wv; N = 256;  KT = 8;  lc = c - CH_WV; }
    else if (c < CH_WO) { W = W1; N = 1024; KT = 8;  lc = c - CH_W1; }
    else if (c < CH_WC) { W = Wo; N = 256;  KT = 32; lc = c - CH_WO; }
    else                { W = Wc; N = 256;  KT = 8;  lc = c - CH_WC; }
    int lane = lc & 63, tmp = lc >> 6;
    int kt = tmp % KT, nt = tmp / KT;
    int k0 = kt * 32 + (lane >> 4) * 8;
    int n  = nt * 16 + (lane & 15);
    bf16x8 v;
    #pragma unroll
    for (int j = 0; j < 8; ++j) v[j] = (bf16)W[(size_t)(k0 + j) * N + n];
    *(bf16x8*)(ws + (size_t)c * 8) = v;
}

__device__ __forceinline__ bf16x8 lds_afrag(const bf16* smb, int baseoff, int KT,
                                            int mt, int kt, int lane) {
    return *(const bf16x8*)(smb + baseoff + (((mt * KT + kt) * 64) + lane) * 8);
}

__device__ __forceinline__ const bf16* qkv_wptr(const bf16* ws, int g, int lane) {
    int ch;
    if (g < 32)      ch = CH_WQ + g * 512;          // chunk units: g*KT*64
    else if (g < 64) ch = CH_WK + (g - 32) * 512;
    else             ch = CH_WV + (g - 64) * 512;
    return ws + ((size_t)ch + lane) * 8;
}

__device__ __forceinline__ void qkv_epi(bf16* smb, int g, int col, int qd,
                                        const float* __restrict__ bq,
                                        const float* __restrict__ bk,
                                        const float* __restrict__ bv,
                                        const f32x4& m0, const f32x4& m1) {
    int plane, stride, chan; float bias;
    if (g < 32)      { chan = g * 16 + col;        bias = bq[chan]; plane = L_QS; stride = 528; }
    else if (g < 64) { chan = (g - 32) * 16 + col; bias = bk[chan]; plane = L_KS; stride = 528; }
    else             { chan = (g - 64) * 16 + col; bias = bv[chan]; plane = L_VS; stride = 272; }
    #pragma unroll
    for (int r = 0; r < 4; ++r) {
        smb[plane + (qd * 4 + r) * stride + chan]        = (bf16)(m0[r] + bias);
        smb[plane + (16 + qd * 4 + r) * stride + chan]   = (bf16)(m1[r] + bias);
    }
}

// stage-1 pass, 2 n-tiles, depth-2 named prefetch. live ~50 regs.
__device__ __forceinline__ void qkv_pass2(bf16* smb, const bf16* __restrict__ ws,
                                          int wave, int lane, int col, int qd, int i0,
                                          const float* __restrict__ bq,
                                          const float* __restrict__ bk,
                                          const float* __restrict__ bv) {
    const int g0 = wave * 5 + i0, g1 = g0 + 1;
    const bf16* w0 = qkv_wptr(ws, g0, lane);
    const bf16* w1 = qkv_wptr(ws, g1, lane);
    f32x4 a00 = (f32x4){0.f,0.f,0.f,0.f}, a01 = (f32x4){0.f,0.f,0.f,0.f};
    f32x4 a10 = (f32x4){0.f,0.f,0.f,0.f}, a11 = (f32x4){0.f,0.f,0.f,0.f};
    bf16x8 b0 = *(const bf16x8*)(w0);
    bf16x8 b1 = *(const bf16x8*)(w1);
    #pragma unroll
    for (int kt = 0; kt < 8; ++kt) {
        bf16x8 n0 = b0, n1 = b1;
        if (kt < 7) {
            n0 = *(const bf16x8*)(w0 + (kt + 1) * 512);
            n1 = *(const bf16x8*)(w1 + (kt + 1) * 512);
        }
        bf16x8 x0 = lds_afrag(smb, L_XF, 8, 0, kt, lane);
        bf16x8 x1 = lds_afrag(smb, L_XF, 8, 1, kt, lane);
        a00 = MFMA(x0, b0, a00); a01 = MFMA(x1, b0, a01);
        a10 = MFMA(x0, b1, a10); a11 = MFMA(x1, b1, a11);
        b0 = n0; b1 = n1;
    }
    qkv_epi(smb, g0, col, qd, bq, bk, bv, a00, a01);
    qkv_epi(smb, g1, col, qd, bq, bk, bv, a10, a11);
}

// stage-1 pass, 1 n-tile, depth-2.
__device__ __forceinline__ void qkv_pass1(bf16* smb, const bf16* __restrict__ ws,
                                          int wave, int lane, int col, int qd, int i0,
                                          const float* __restrict__ bq,
                                          const float* __restrict__ bk,
                                          const float* __restrict__ bv) {
    const int g0 = wave * 5 + i0;
    const bf16* w0 = qkv_wptr(ws, g0, lane);
    f32x4 a00 = (f32x4){0.f,0.f,0.f,0.f}, a01 = (f32x4){0.f,0.f,0.f,0.f};
    bf16x8 b0 = *(const bf16x8*)(w0);
    #pragma unroll
    for (int kt = 0; kt < 8; ++kt) {
        bf16x8 n0 = b0;
        if (kt < 7) n0 = *(const bf16x8*)(w0 + (kt + 1) * 512);
        bf16x8 x0 = lds_afrag(smb, L_XF, 8, 0, kt, lane);
        bf16x8 x1 = lds_afrag(smb, L_XF, 8, 1, kt, lane);
        a00 = MFMA(x0, b0, a00); a01 = MFMA(x1, b0, a01);
        b0 = n0;
    }
    qkv_epi(smb, g0, col, qd, bq, bk, bv, a00, a01);
}

// stage-3 pass, 2 n-tiles (t0, t0+1), depth-2 named prefetch.
__device__ __forceinline__ void ffn1_pass2(bf16* smb, const bf16* __restrict__ ws,
                                           int lane, int col, int qd, int t0,
                                           const float* __restrict__ b1v) {
    const bf16* w0 = ws + ((size_t)(CH_W1 + t0 * 512) + lane) * 8;
    const bf16* w1 = ws + ((size_t)(CH_W1 + (t0 + 1) * 512) + lane) * 8;
    f32x4 a00 = (f32x4){0.f,0.f,0.f,0.f}, a01 = (f32x4){0.f,0.f,0.f,0.f};
    f32x4 a10 = (f32x4){0.f,0.f,0.f,0.f}, a11 = (f32x4){0.f,0.f,0.f,0.f};
    bf16x8 b0 = *(const bf16x8*)(w0);
    bf16x8 b1 = *(const bf16x8*)(w1);
    #pragma unroll
    for (int kt = 0; kt < 8; ++kt) {
        bf16x8 n0 = b0, n1 = b1;
        if (kt < 7) {
            n0 = *(const bf16x8*)(w0 + (kt + 1) * 512);
            n1 = *(const bf16x8*)(w1 + (kt + 1) * 512);
        }
        bf16x8 x0 = lds_afrag(smb, L_AOF, 8, 0, kt, lane);
        bf16x8 x1 = lds_afrag(smb, L_AOF, 8, 1, kt, lane);
        a00 = MFMA(x0, b0, a00); a01 = MFMA(x1, b0, a01);
        a10 = MFMA(x0, b1, a10); a11 = MFMA(x1, b1, a11);
        b0 = n0; b1 = n1;
    }
    #pragma unroll
    for (int i = 0; i < 2; ++i) {
        int c = (t0 + i) * 16 + col;
        float bias = b1v[c];
        int kt2 = c >> 5;
        int q2  = (c & 31) >> 3;
        int j2  = c & 7;
        #pragma unroll
        for (int r = 0; r < 4; ++r) {
            float v0 = fmaxf((i ? a10[r] : a00[r]) + bias, 0.f);
            float v1 = fmaxf((i ? a11[r] : a01[r]) + bias, 0.f);
            int m0_ = qd * 4 + r;
            smb[L_INTF + (((0 * 32 + kt2) * 64) + q2 * 16 + m0_) * 8 + j2] = (bf16)v0;
            smb[L_INTF + (((1 * 32 + kt2) * 64) + q2 * 16 + m0_) * 8 + j2] = (bf16)v1;
        }
    }
}

__global__ __launch_bounds__(THREADS)
__attribute__((amdgpu_waves_per_eu(4, 4)))
void msa_mfma(const float* __restrict__ x, const bf16* __restrict__ ws,
              const float* __restrict__ bq, const float* __restrict__ bk,
              const float* __restrict__ bv, const float* __restrict__ b1,
              const float* __restrict__ bo, const float* __restrict__ bc,
              const float* __restrict__ gamma, const float* __restrict__ beta,
              const float* __restrict__ mu, const float* __restrict__ var,
              float* __restrict__ out)
{
    extern __shared__ bf16 smb[];
    const int t = threadIdx.x;
    const int lane = t & 63;
    const int wave = t >> 6;                 // 0..15
    const int col = lane & 15;
    const int qd  = lane >> 4;
    const size_t base = (size_t)blockIdx.x * (TILE * CIN);

    // ---- stage 0: load x, convert to bf16, store in A-frag order ----
    // 1024 chunks, exactly one per thread
    {
        int c2 = t;
        int lc = c2 & 63, kt = (c2 >> 6) & 7, mt = c2 >> 9;
        int vox = mt * 16 + (lc & 15);
        int k0  = kt * 32 + (lc >> 4) * 8;
        const float* src = x + base + vox * 256 + k0;
        float4 f0 = *(const float4*)src;
        float4 f1 = *(const float4*)(src + 4);
        bf16x8 h;
        h[0] = (bf16)f0.x; h[1] = (bf16)f0.y; h[2] = (bf16)f0.z; h[3] = (bf16)f0.w;
        h[4] = (bf16)f1.x; h[5] = (bf16)f1.y; h[6] = (bf16)f1.z; h[7] = (bf16)f1.w;
        *(bf16x8*)&smb[L_XF + c2 * 8] = h;
    }
    __syncthreads();

    // ---- stage 1: QKV GEMM. 80 n-tiles (q:0-31, k:32-63, v:64-79), 5/wave,
    //      pipelined passes 2+2+1 (named-scalar depth-2 prefetch) ----
    qkv_pass2(smb, ws, wave, lane, col, qd, 0, bq, bk, bv);
    qkv_pass2(smb, ws, wave, lane, col, qd, 2, bq, bk, bv);
    qkv_pass1(smb, ws, wave, lane, col, qd, 4, bq, bk, bv);
    __syncthreads();

    // ---- stage 2: attention, pair-split: thread = (vox, head, half) ----
    // 32 vox * 16 heads * 2 halves = 1024 threads, all active.
    // Each thread covers 8 of the 16 key-heads; shfl_xor(1) merges stats.
    // ALL private arrays statically indexed (rule #20): ao split lo/hi.
    {
        const int half = t & 1;
        const int h   = (t >> 1) & 15;
        const int vox = t >> 5;
        const bf16* qp  = smb + L_QS + vox * 528 + h * 32;
        const bf16* kp0 = smb + L_KS + vox * 528 + (half * 8) * 32;
        float sc_[8];
        #pragma unroll
        for (int gg = 0; gg < 8; ++gg) sc_[gg] = 0.f;
        #pragma unroll
        for (int d8 = 0; d8 < 4; ++d8) {
            bf16x8 qv = *(const bf16x8*)(qp + d8 * 8);
            float qf[8];
            #pragma unroll
            for (int j = 0; j < 8; ++j) qf[j] = (float)qv[j];
            #pragma unroll
            for (int gg = 0; gg < 8; ++gg) {
                bf16x8 kv = *(const bf16x8*)(kp0 + gg * 32 + d8 * 8);  // broadcast across h
                #pragma unroll
                for (int j = 0; j < 8; ++j) sc_[gg] = fmaf((float)kv[j], qf[j], sc_[gg]);
            }
        }
        #pragma unroll
        for (int gg = 0; gg < 8; ++gg) sc_[gg] *= 0.17677669529663687f;  // 1/sqrt(32)
        float m = sc_[0];
        #pragma unroll
        for (int gg = 1; gg < 8; ++gg) m = fmaxf(m, sc_[gg]);
        m = fmaxf(m, __shfl_xor(m, 1));
        float sum = 0.f;
        #pragma unroll
        for (int gg = 0; gg < 8; ++gg) { sc_[gg] = __expf(sc_[gg] - m); sum += sc_[gg]; }
        sum += __shfl_xor(sum, 1);
        const float inv = 1.f / sum;
        // AV accumulation: two statically-indexed 8-float halves (dv 0-7, 8-15)
        float ao_lo[8], ao_hi[8];
        #pragma unroll
        for (int j = 0; j < 8; ++j) { ao_lo[j] = 0.f; ao_hi[j] = 0.f; }
        #pragma unroll
        for (int gg = 0; gg < 8; ++gg) {
            const float a = sc_[gg];
            const bf16* vp = smb + L_VS + vox * 272 + (half * 8 + gg) * 16;  // broadcast across h
            bf16x8 v0 = *(const bf16x8*)(vp);
            bf16x8 v1 = *(const bf16x8*)(vp + 8);
            #pragma unroll
            for (int j = 0; j < 8; ++j) {
                ao_lo[j] = fmaf(a, (float)v0[j], ao_lo[j]);
                ao_hi[j] = fmaf(a, (float)v1[j], ao_hi[j]);
            }
        }
        // merge the two halves' AV partials (both lanes end with full sums)
        #pragma unroll
        for (int j = 0; j < 8; ++j) {
            ao_lo[j] += __shfl_xor(ao_lo[j], 1);
            ao_hi[j] += __shfl_xor(ao_hi[j], 1);
        }
        // write own dv-half in A-frag order for FFN1: chan c = h*16 + half*8 + j
        const int mt = vox >> 4, m_ = vox & 15, kt = h >> 1;
        const int quad = (h & 1) * 2 + half;
        bf16x8 o;
        #pragma unroll
        for (int j = 0; j < 8; ++j) {
            float v = half ? ao_hi[j] : ao_lo[j];   // per-element cndmask, no indexing
            o[j] = (bf16)(v * inv);
        }
        *(bf16x8*)&smb[L_AOF + (((mt * 8 + kt) * 64) + quad * 16 + m_) * 8] = o;
    }
    __syncthreads();

    // ---- stage 3: FFN1 = relu(ao @ W1 + b1) -> inter A-frags.
    //      64 n-tiles, 4/wave, two pipelined passes of 2 ----
    // NOTE: no extra barrier needed before writing L_INTF — all q/k/v reads
    // completed before the stage2->3 __syncthreads above, and stage-3 waves
    // write channel-disjoint L_INTF ranges.
    ffn1_pass2(smb, ws, lane, col, qd, wave * 4, b1);
    ffn1_pass2(smb, ws, lane, col, qd, wave * 4 + 2, b1);
    __syncthreads();

    // ---- stage 4: FFN2 (inter @ Wo) + residual (x @ Wc) + batchnorm.
    //      1 n-tile/wave; named depth-3 rotating prefetch per stream ----
    {
        const int n0 = wave;
        f32x4 aF0 = (f32x4){0.f,0.f,0.f,0.f}, aF1 = (f32x4){0.f,0.f,0.f,0.f};
        f32x4 aW0 = (f32x4){0.f,0.f,0.f,0.f}, aW1 = (f32x4){0.f,0.f,0.f,0.f};
        {
            const bf16* wf = ws + ((size_t)(CH_WO + n0 * 32 * 64) + lane) * 8;
            bf16x8 b0 = *(const bf16x8*)(wf);
            bf16x8 b1 = *(const bf16x8*)(wf + 512);
            #pragma unroll
            for (int kt = 0; kt < 32; ++kt) {
                bf16x8 b2 = b1;
                if (kt < 30) b2 = *(const bf16x8*)(wf + (kt + 2) * 512);
                bf16x8 x0 = lds_afrag(smb, L_INTF, 32, 0, kt, lane);
                bf16x8 x1 = lds_afrag(smb, L_INTF, 32, 1, kt, lane);
                aF0 = MFMA(x0, b0, aF0);
                aF1 = MFMA(x1, b0, aF1);
                b0 = b1; b1 = b2;
            }
        }
        {
            const bf16* ww = ws + ((size_t)(CH_WC + n0 * 8 * 64) + lane) * 8;
            bf16x8 b0 = *(const bf16x8*)(ww);
            bf16x8 b1 = *(const bf16x8*)(ww + 512);
            #pragma unroll
            for (int kt = 0; kt < 8; ++kt) {
                bf16x8 b2 = b1;
                if (kt < 6) b2 = *(const bf16x8*)(ww + (kt + 2) * 512);
                bf16x8 x0 = lds_afrag(smb, L_XF, 8, 0, kt, lane);
                bf16x8 x1 = lds_afrag(smb, L_XF, 8, 1, kt, lane);
                aW0 = MFMA(x0, b0, aW0);
                aW1 = MFMA(x1, b0, aW1);
                b0 = b1; b1 = b2;
            }
        }
        {
            int c = n0 * 16 + col;
            float bo_ = bo[c], bc_ = bc[c];
            float scl = gamma[c] * rsqrtf(var[c] + 1e-6f);
            float mu_ = mu[c], be_ = beta[c];
            #pragma unroll
            for (int r = 0; r < 4; ++r) {
                int vox0 = qd * 4 + r;
                float res0 = fmaxf(aW0[r] + bc_, 0.f);
                float iv0  = aF0[r] + bo_;
                out[base + vox0 * 256 + c] = (res0 + iv0 - mu_) * scl + be_;
                int vox1 = 16 + qd * 4 + r;
                float res1 = fmaxf(aW1[r] + bc_, 0.f);
                float iv1  = aF1[r] + bo_;
                out[base + vox1 * 256 + c] = (res1 + iv1 - mu_) * scl + be_;
            }
        }
    }
}

extern "C" void kernel_launch(void* const* d_in, const int* in_sizes, int n_in,
                              void* d_out, int out_size, void* d_ws, size_t ws_size,
                              hipStream_t stream) {
    const float* x     = (const float*)d_in[0];
    const float* Wq    = (const float*)d_in[1];
    const float* bq    = (const float*)d_in[2];
    const float* Wk    = (const float*)d_in[3];
    const float* bk    = (const float*)d_in[4];
    const float* Wv    = (const float*)d_in[5];
    const float* bv    = (const float*)d_in[6];
    const float* W1    = (const float*)d_in[7];
    const float* b1    = (const float*)d_in[8];
    const float* Wo    = (const float*)d_in[9];
    const float* bo    = (const float*)d_in[10];
    const float* Wc    = (const float*)d_in[11];
    const float* bc    = (const float*)d_in[12];
    const float* gamma = (const float*)d_in[13];
    const float* beta  = (const float*)d_in[14];
    const float* mu    = (const float*)d_in[15];
    const float* var   = (const float*)d_in[16];
    float* out = (float*)d_out;
    bf16* ws = (bf16*)d_ws;

    pack_w<<<(CH_TOT + 255) / 256, 256, 0, stream>>>(Wq, Wk, Wv, W1, Wo, Wc, ws);

    const int n = in_sizes[0] / CIN;           // 131072 voxels
    const int blocks = n / TILE;               // 4096
    const size_t smem = LDS_ELEMS * sizeof(bf16);  // 117760 B
    hipFuncSetAttribute(reinterpret_cast<const void*>(msa_mfma),
                        hipFuncAttributeMaxDynamicSharedMemorySize, (int)smem);
    msa_mfma<<<blocks, THREADS, smem, stream>>>(x, ws, bq, bk, bv, b1, bo, bc,
                                                gamma, beta, mu, var, out);
}

// Round 8
// 644.369 us; speedup vs baseline: 1.0631x; 1.0631x over previous
//
#include <hip/hip_runtime.h>
#include <hip/hip_bf16.h>

// MSAAttentionBlock round 9: third pipelining attempt, sized for the 64-VGPR
// allocator wall (rounds 6/7 both spilled at 64). GN=1 passes, depth-4
// B-prefetch in LONGHAND named registers: peak live ~40 (acc 8 + b0-b3 16 +
// A 8 + ptr), leaving ~16 regs of cushion for epilogue/address temps.
//   stage 1: 5 passes of 1 n-tile, depth-4
//   stage 3: 4 passes of 1 n-tile, depth-4
//   stage 4: Wo KT=32 and Wc KT=8, manual 4-step unroll, depth-4
// Cost: XF/AOF re-read per pass (+~2% LDS traffic). Stage 0/2, layouts,
// barriers identical to the clean 471 µs round-5 kernel.
// Scratch tripwire: WRITE_SIZE must stay exactly 131072 KB.

typedef __bf16 bf16;
typedef __bf16 bf16x8 __attribute__((ext_vector_type(8)));
typedef float f32x4 __attribute__((ext_vector_type(4)));

#define MFMA(a, b, c) __builtin_amdgcn_mfma_f32_16x16x32_bf16((a), (b), (c), 0, 0, 0)

#define THREADS 1024
#define TILE 32

constexpr int CIN = 256;

// packed-weight regions, in 8-element chunks (chunk = 16 B)
// layout per matrix: chunk lc = (nt*KT + kt)*64 + lane ; elems at lc*8
//   element j of chunk: B[k = kt*32 + (lane>>4)*8 + j][n = nt*16 + (lane&15)]
constexpr int CH_WQ = 0;                // 256x512  -> 16384 chunks, KT=8
constexpr int CH_WK = 16384;            // 256x512
constexpr int CH_WV = 32768;            // 256x256  -> 8192
constexpr int CH_W1 = 40960;            // 256x1024 -> 32768
constexpr int CH_WO = 73728;            // 1024x256 -> 32768, KT=32
constexpr int CH_WC = 106496;           // 256x256  -> 8192
constexpr int CH_TOT = 114688;          // * 16 B = 1.75 MB

// LDS layout (bf16 element offsets)
constexpr int L_XF  = 0;                // x A-frags:  2*8*64*8 = 8192
constexpr int L_AOF = 8192;             // ao A-frags: 8192
constexpr int L_C   = 16384;            // overlay region
constexpr int L_QS  = L_C;              // q plain [32][528]
constexpr int L_KS  = L_C + 16896;      // k plain [32][528]
constexpr int L_VS  = L_C + 33792;      // v plain [32][272]
constexpr int L_INTF = L_C;             // inter A-frags 2*32*64*8 = 32768 (aliases q/k/v)
constexpr int LDS_ELEMS = 16384 + 42496;   // 58880 bf16 = 117760 B -> 1 block/CU, 16 waves

__global__ void pack_w(const float* __restrict__ Wq, const float* __restrict__ Wk,
                       const float* __restrict__ Wv, const float* __restrict__ W1,
                       const float* __restrict__ Wo, const float* __restrict__ Wc,
                       bf16* __restrict__ ws) {
    int c = blockIdx.x * 256 + threadIdx.x;
    if (c >= CH_TOT) return;
    const float* W; int N, KT, lc;
    if (c < CH_WK)      { W = Wq; N = 512;  KT = 8;  lc = c - CH_WQ; }
    else if (c < CH_WV) { W = Wk; N = 512;  KT = 8;  lc = c - CH_WK; }
    else if (c < CH_W1) { W = Wv; N = 256;  KT = 8;  lc = c - CH_WV; }
    else if (c < CH_WO) { W = W1; N = 1024; KT = 8;  lc = c - CH_W1; }
    else if (c < CH_WC) { W = Wo; N = 256;  KT = 32; lc = c - CH_WO; }
    else                { W = Wc; N = 256;  KT = 8;  lc = c - CH_WC; }
    int lane = lc & 63, tmp = lc >> 6;
    int kt = tmp % KT, nt = tmp / KT;
    int k0 = kt * 32 + (lane >> 4) * 8;
    int n  = nt * 16 + (lane & 15);
    bf16x8 v;
    #pragma unroll
    for (int j = 0; j < 8; ++j) v[j] = (bf16)W[(size_t)(k0 + j) * N + n];
    *(bf16x8*)(ws + (size_t)c * 8) = v;
}

__device__ __forceinline__ bf16x8 lds_afrag(const bf16* smb, int baseoff, int KT,
                                            int mt, int kt, int lane) {
    return *(const bf16x8*)(smb + baseoff + (((mt * KT + kt) * 64) + lane) * 8);
}

// GN=1, KT=8, depth-4 pipelined GEMM over one packed B stream (longhand
// named registers; peak live ~40). acc covers both m-tiles.
__device__ __forceinline__ void gemm1_k8_d4(const bf16* smb, int abase,
                                            const bf16* __restrict__ w, int lane,
                                            f32x4& a0, f32x4& a1) {
    bf16x8 b0 = *(const bf16x8*)(w + 0 * 512);
    bf16x8 b1 = *(const bf16x8*)(w + 1 * 512);
    bf16x8 b2 = *(const bf16x8*)(w + 2 * 512);
    bf16x8 b3 = *(const bf16x8*)(w + 3 * 512);
    bf16x8 x0, x1;
    // k=0 (reload b0 <- k4)
    x0 = lds_afrag(smb, abase, 8, 0, 0, lane); x1 = lds_afrag(smb, abase, 8, 1, 0, lane);
    a0 = MFMA(x0, b0, a0); a1 = MFMA(x1, b0, a1);
    b0 = *(const bf16x8*)(w + 4 * 512);
    // k=1
    x0 = lds_afrag(smb, abase, 8, 0, 1, lane); x1 = lds_afrag(smb, abase, 8, 1, 1, lane);
    a0 = MFMA(x0, b1, a0); a1 = MFMA(x1, b1, a1);
    b1 = *(const bf16x8*)(w + 5 * 512);
    // k=2
    x0 = lds_afrag(smb, abase, 8, 0, 2, lane); x1 = lds_afrag(smb, abase, 8, 1, 2, lane);
    a0 = MFMA(x0, b2, a0); a1 = MFMA(x1, b2, a1);
    b2 = *(const bf16x8*)(w + 6 * 512);
    // k=3
    x0 = lds_afrag(smb, abase, 8, 0, 3, lane); x1 = lds_afrag(smb, abase, 8, 1, 3, lane);
    a0 = MFMA(x0, b3, a0); a1 = MFMA(x1, b3, a1);
    b3 = *(const bf16x8*)(w + 7 * 512);
    // k=4..7 (no reload)
    x0 = lds_afrag(smb, abase, 8, 0, 4, lane); x1 = lds_afrag(smb, abase, 8, 1, 4, lane);
    a0 = MFMA(x0, b0, a0); a1 = MFMA(x1, b0, a1);
    x0 = lds_afrag(smb, abase, 8, 0, 5, lane); x1 = lds_afrag(smb, abase, 8, 1, 5, lane);
    a0 = MFMA(x0, b1, a0); a1 = MFMA(x1, b1, a1);
    x0 = lds_afrag(smb, abase, 8, 0, 6, lane); x1 = lds_afrag(smb, abase, 8, 1, 6, lane);
    a0 = MFMA(x0, b2, a0); a1 = MFMA(x1, b2, a1);
    x0 = lds_afrag(smb, abase, 8, 0, 7, lane); x1 = lds_afrag(smb, abase, 8, 1, 7, lane);
    a0 = MFMA(x0, b3, a0); a1 = MFMA(x1, b3, a1);
}

__device__ __forceinline__ const bf16* qkv_wptr(const bf16* ws, int g, int lane) {
    int ch;
    if (g < 32)      ch = CH_WQ + g * 512;          // chunk units: g*KT*64
    else if (g < 64) ch = CH_WK + (g - 32) * 512;
    else             ch = CH_WV + (g - 64) * 512;
    return ws + ((size_t)ch + lane) * 8;
}

__device__ __forceinline__ void qkv_epi(bf16* smb, int g, int col, int qd,
                                        const float* __restrict__ bq,
                                        const float* __restrict__ bk,
                                        const float* __restrict__ bv,
                                        const f32x4& m0, const f32x4& m1) {
    int plane, stride, chan; float bias;
    if (g < 32)      { chan = g * 16 + col;        bias = bq[chan]; plane = L_QS; stride = 528; }
    else if (g < 64) { chan = (g - 32) * 16 + col; bias = bk[chan]; plane = L_KS; stride = 528; }
    else             { chan = (g - 64) * 16 + col; bias = bv[chan]; plane = L_VS; stride = 272; }
    #pragma unroll
    for (int r = 0; r < 4; ++r) {
        smb[plane + (qd * 4 + r) * stride + chan]      = (bf16)(m0[r] + bias);
        smb[plane + (16 + qd * 4 + r) * stride + chan] = (bf16)(m1[r] + bias);
    }
}

__global__ __launch_bounds__(THREADS)
__attribute__((amdgpu_waves_per_eu(4, 4)))
void msa_mfma(const float* __restrict__ x, const bf16* __restrict__ ws,
              const float* __restrict__ bq, const float* __restrict__ bk,
              const float* __restrict__ bv, const float* __restrict__ b1,
              const float* __restrict__ bo, const float* __restrict__ bc,
              const float* __restrict__ gamma, const float* __restrict__ beta,
              const float* __restrict__ mu, const float* __restrict__ var,
              float* __restrict__ out)
{
    extern __shared__ bf16 smb[];
    const int t = threadIdx.x;
    const int lane = t & 63;
    const int wave = t >> 6;                 // 0..15
    const int col = lane & 15;
    const int qd  = lane >> 4;
    const size_t base = (size_t)blockIdx.x * (TILE * CIN);

    // ---- stage 0: load x, convert to bf16, store in A-frag order ----
    // 1024 chunks, exactly one per thread
    {
        int c2 = t;
        int lc = c2 & 63, kt = (c2 >> 6) & 7, mt = c2 >> 9;
        int vox = mt * 16 + (lc & 15);
        int k0  = kt * 32 + (lc >> 4) * 8;
        const float* src = x + base + vox * 256 + k0;
        float4 f0 = *(const float4*)src;
        float4 f1 = *(const float4*)(src + 4);
        bf16x8 h;
        h[0] = (bf16)f0.x; h[1] = (bf16)f0.y; h[2] = (bf16)f0.z; h[3] = (bf16)f0.w;
        h[4] = (bf16)f1.x; h[5] = (bf16)f1.y; h[6] = (bf16)f1.z; h[7] = (bf16)f1.w;
        *(bf16x8*)&smb[L_XF + c2 * 8] = h;
    }
    __syncthreads();

    // ---- stage 1: QKV GEMM. 80 n-tiles (q:0-31, k:32-63, v:64-79), 5/wave,
    //      five GN=1 depth-4 pipelined passes ----
    #pragma unroll
    for (int i = 0; i < 5; ++i) {
        const int g = wave * 5 + i;
        const bf16* w = qkv_wptr(ws, g, lane);
        f32x4 a0 = (f32x4){0.f, 0.f, 0.f, 0.f};
        f32x4 a1 = (f32x4){0.f, 0.f, 0.f, 0.f};
        gemm1_k8_d4(smb, L_XF, w, lane, a0, a1);
        qkv_epi(smb, g, col, qd, bq, bk, bv, a0, a1);
    }
    __syncthreads();

    // ---- stage 2: attention, pair-split: thread = (vox, head, half) ----
    // 32 vox * 16 heads * 2 halves = 1024 threads, all active.
    // Each thread covers 8 of the 16 key-heads; shfl_xor(1) merges stats.
    // ALL private arrays statically indexed (rule #20): ao split lo/hi.
    {
        const int half = t & 1;
        const int h   = (t >> 1) & 15;
        const int vox = t >> 5;
        const bf16* qp  = smb + L_QS + vox * 528 + h * 32;
        const bf16* kp0 = smb + L_KS + vox * 528 + (half * 8) * 32;
        float sc_[8];
        #pragma unroll
        for (int gg = 0; gg < 8; ++gg) sc_[gg] = 0.f;
        #pragma unroll
        for (int d8 = 0; d8 < 4; ++d8) {
            bf16x8 qv = *(const bf16x8*)(qp + d8 * 8);
            float qf[8];
            #pragma unroll
            for (int j = 0; j < 8; ++j) qf[j] = (float)qv[j];
            #pragma unroll
            for (int gg = 0; gg < 8; ++gg) {
                bf16x8 kv = *(const bf16x8*)(kp0 + gg * 32 + d8 * 8);  // broadcast across h
                #pragma unroll
                for (int j = 0; j < 8; ++j) sc_[gg] = fmaf((float)kv[j], qf[j], sc_[gg]);
            }
        }
        #pragma unroll
        for (int gg = 0; gg < 8; ++gg) sc_[gg] *= 0.17677669529663687f;  // 1/sqrt(32)
        float m = sc_[0];
        #pragma unroll
        for (int gg = 1; gg < 8; ++gg) m = fmaxf(m, sc_[gg]);
        m = fmaxf(m, __shfl_xor(m, 1));
        float sum = 0.f;
        #pragma unroll
        for (int gg = 0; gg < 8; ++gg) { sc_[gg] = __expf(sc_[gg] - m); sum += sc_[gg]; }
        sum += __shfl_xor(sum, 1);
        const float inv = 1.f / sum;
        // AV accumulation: two statically-indexed 8-float halves (dv 0-7, 8-15)
        float ao_lo[8], ao_hi[8];
        #pragma unroll
        for (int j = 0; j < 8; ++j) { ao_lo[j] = 0.f; ao_hi[j] = 0.f; }
        #pragma unroll
        for (int gg = 0; gg < 8; ++gg) {
            const float a = sc_[gg];
            const bf16* vp = smb + L_VS + vox * 272 + (half * 8 + gg) * 16;  // broadcast across h
            bf16x8 v0 = *(const bf16x8*)(vp);
            bf16x8 v1 = *(const bf16x8*)(vp + 8);
            #pragma unroll
            for (int j = 0; j < 8; ++j) {
                ao_lo[j] = fmaf(a, (float)v0[j], ao_lo[j]);
                ao_hi[j] = fmaf(a, (float)v1[j], ao_hi[j]);
            }
        }
        // merge the two halves' AV partials (both lanes end with full sums)
        #pragma unroll
        for (int j = 0; j < 8; ++j) {
            ao_lo[j] += __shfl_xor(ao_lo[j], 1);
            ao_hi[j] += __shfl_xor(ao_hi[j], 1);
        }
        // write own dv-half in A-frag order for FFN1: chan c = h*16 + half*8 + j
        const int mt = vox >> 4, m_ = vox & 15, kt = h >> 1;
        const int quad = (h & 1) * 2 + half;
        bf16x8 o;
        #pragma unroll
        for (int j = 0; j < 8; ++j) {
            float v = half ? ao_hi[j] : ao_lo[j];   // per-element cndmask, no indexing
            o[j] = (bf16)(v * inv);
        }
        *(bf16x8*)&smb[L_AOF + (((mt * 8 + kt) * 64) + quad * 16 + m_) * 8] = o;
    }
    __syncthreads();

    // ---- stage 3: FFN1 = relu(ao @ W1 + b1) -> inter A-frags.
    //      64 n-tiles, 4/wave, four GN=1 depth-4 pipelined passes ----
    // NOTE: no extra barrier needed before writing L_INTF — all q/k/v reads
    // completed before the stage2->3 __syncthreads above, and stage-3 waves
    // write channel-disjoint L_INTF ranges.
    #pragma unroll
    for (int i = 0; i < 4; ++i) {
        const int tt = wave * 4 + i;
        const bf16* w = ws + ((size_t)(CH_W1 + tt * 512) + lane) * 8;
        f32x4 a0 = (f32x4){0.f, 0.f, 0.f, 0.f};
        f32x4 a1 = (f32x4){0.f, 0.f, 0.f, 0.f};
        gemm1_k8_d4(smb, L_AOF, w, lane, a0, a1);
        int c = tt * 16 + col;
        float bias = b1[c];
        int kt2 = c >> 5;
        int q2  = (c & 31) >> 3;
        int j2  = c & 7;
        #pragma unroll
        for (int r = 0; r < 4; ++r) {
            int m_ = qd * 4 + r;
            float v0 = fmaxf(a0[r] + bias, 0.f);
            float v1 = fmaxf(a1[r] + bias, 0.f);
            smb[L_INTF + (((0 * 32 + kt2) * 64) + q2 * 16 + m_) * 8 + j2] = (bf16)v0;
            smb[L_INTF + (((1 * 32 + kt2) * 64) + q2 * 16 + m_) * 8 + j2] = (bf16)v1;
        }
    }
    __syncthreads();

    // ---- stage 4: FFN2 (inter @ Wo) + residual (x @ Wc) + batchnorm.
    //      1 n-tile/wave; Wo KT=32 manual 4-step unroll depth-4; Wc depth-4 ----
    {
        const int n0 = wave;
        f32x4 aF0 = (f32x4){0.f,0.f,0.f,0.f}, aF1 = (f32x4){0.f,0.f,0.f,0.f};
        f32x4 aW0 = (f32x4){0.f,0.f,0.f,0.f}, aW1 = (f32x4){0.f,0.f,0.f,0.f};
        {
            const bf16* wf = ws + ((size_t)(CH_WO + n0 * 32 * 64) + lane) * 8;
            bf16x8 b0 = *(const bf16x8*)(wf + 0 * 512);
            bf16x8 b1 = *(const bf16x8*)(wf + 1 * 512);
            bf16x8 b2 = *(const bf16x8*)(wf + 2 * 512);
            bf16x8 b3 = *(const bf16x8*)(wf + 3 * 512);
            #pragma unroll
            for (int kb = 0; kb < 8; ++kb) {
                const int k = kb * 4;
                bf16x8 x0, x1;
                x0 = lds_afrag(smb, L_INTF, 32, 0, k + 0, lane);
                x1 = lds_afrag(smb, L_INTF, 32, 1, k + 0, lane);
                aF0 = MFMA(x0, b0, aF0); aF1 = MFMA(x1, b0, aF1);
                if (kb < 7) b0 = *(const bf16x8*)(wf + (k + 4) * 512);
                x0 = lds_afrag(smb, L_INTF, 32, 0, k + 1, lane);
                x1 = lds_afrag(smb, L_INTF, 32, 1, k + 1, lane);
                aF0 = MFMA(x0, b1, aF0); aF1 = MFMA(x1, b1, aF1);
                if (kb < 7) b1 = *(const bf16x8*)(wf + (k + 5) * 512);
                x0 = lds_afrag(smb, L_INTF, 32, 0, k + 2, lane);
                x1 = lds_afrag(smb, L_INTF, 32, 1, k + 2, lane);
                aF0 = MFMA(x0, b2, aF0); aF1 = MFMA(x1, b2, aF1);
                if (kb < 7) b2 = *(const bf16x8*)(wf + (k + 6) * 512);
                x0 = lds_afrag(smb, L_INTF, 32, 0, k + 3, lane);
                x1 = lds_afrag(smb, L_INTF, 32, 1, k + 3, lane);
                aF0 = MFMA(x0, b3, aF0); aF1 = MFMA(x1, b3, aF1);
                if (kb < 7) b3 = *(const bf16x8*)(wf + (k + 7) * 512);
            }
        }
        {
            const bf16* ww = ws + ((size_t)(CH_WC + n0 * 8 * 64) + lane) * 8;
            gemm1_k8_d4(smb, L_XF, ww, lane, aW0, aW1);
        }
        {
            int c = n0 * 16 + col;
            float bo_ = bo[c], bc_ = bc[c];
            float scl = gamma[c] * rsqrtf(var[c] + 1e-6f);
            float mu_ = mu[c], be_ = beta[c];
            #pragma unroll
            for (int r = 0; r < 4; ++r) {
                int vox0 = qd * 4 + r;
                float res0 = fmaxf(aW0[r] + bc_, 0.f);
                float iv0  = aF0[r] + bo_;
                out[base + vox0 * 256 + c] = (res0 + iv0 - mu_) * scl + be_;
                int vox1 = 16 + qd * 4 + r;
                float res1 = fmaxf(aW1[r] + bc_, 0.f);
                float iv1  = aF1[r] + bo_;
                out[base + vox1 * 256 + c] = (res1 + iv1 - mu_) * scl + be_;
            }
        }
    }
}

extern "C" void kernel_launch(void* const* d_in, const int* in_sizes, int n_in,
                              void* d_out, int out_size, void* d_ws, size_t ws_size,
                              hipStream_t stream) {
    const float* x     = (const float*)d_in[0];
    const float* Wq    = (const float*)d_in[1];
    const float* bq    = (const float*)d_in[2];
    const float* Wk    = (const float*)d_in[3];
    const float* bk    = (const float*)d_in[4];
    const float* Wv    = (const float*)d_in[5];
    const float* bv    = (const float*)d_in[6];
    const float* W1    = (const float*)d_in[7];
    const float* b1    = (const float*)d_in[8];
    const float* Wo    = (const float*)d_in[9];
    const float* bo    = (const float*)d_in[10];
    const float* Wc    = (const float*)d_in[11];
    const float* bc    = (const float*)d_in[12];
    const float* gamma = (const float*)d_in[13];
    const float* beta  = (const float*)d_in[14];
    const float* mu    = (const float*)d_in[15];
    const float* var   = (const float*)d_in[16];
    float* out = (float*)d_out;
    bf16* ws = (bf16*)d_ws;

    pack_w<<<(CH_TOT + 255) / 256, 256, 0, stream>>>(Wq, Wk, Wv, W1, Wo, Wc, ws);

    const int n = in_sizes[0] / CIN;           // 131072 voxels
    const int blocks = n / TILE;               // 4096
    const size_t smem = LDS_ELEMS * sizeof(bf16);  // 117760 B
    hipFuncSetAttribute(reinterpret_cast<const void*>(msa_mfma),
                        hipFuncAttributeMaxDynamicSharedMemorySize, (int)smem);
    msa_mfma<<<blocks, THREADS, smem, stream>>>(x, ws, bq, bk, bv, b1, bo, bc,
                                                gamma, beta, mu, var, out);
}